// Round 4
// baseline (442.557 us; speedup 1.0000x reference)
//
#include <hip/hip_runtime.h>
#include <hip/hip_bf16.h>
#include <math.h>

#define BATCH   32
#define A_TOTAL 8400
#define NCLS    80

typedef __attribute__((ext_vector_type(8))) short bf16x8;
typedef __attribute__((ext_vector_type(4))) float f32x4;

__device__ __forceinline__ short f2bf(float f) {
    union { float f; unsigned u; } v; v.f = f;
    unsigned u = v.u + 0x7fffu + ((v.u >> 16) & 1u);   // round-nearest-even
    return (short)(u >> 16);
}

// async global->LDS, 16B per lane; lds dest = wave-uniform base + lane*16
__device__ __forceinline__ void stage16(const void* g, void* ldsp) {
    __builtin_amdgcn_global_load_lds(
        (const __attribute__((address_space(1))) unsigned int*)g,
        (__attribute__((address_space(3))) unsigned int*)ldsp, 16, 0, 0);
}

// ---------------------------------------------------------------------------
// Weight prep: Afrag[tap][kc][mf(10)][lane(64)][8] bf16, M padded 148->160.
// granule (tap, kc) = contiguous 10KB.
// ---------------------------------------------------------------------------
template<int C>
__global__ __launch_bounds__(256) void prep_w(const float* __restrict__ wc,
                                              const float* __restrict__ wr,
                                              __hip_bfloat16* __restrict__ af) {
    const int KC = C / 32;
    const int total = 9 * KC * 10 * 64;
    int idx = blockIdx.x * 256 + threadIdx.x;
    if (idx >= total) return;
    int l   = idx & 63;
    int rem = idx >> 6;
    int mf  = rem % 10;
    int kc  = (rem / 10) % KC;
    int tap = rem / (10 * KC);
    int m     = mf * 16 + (l & 15);
    int cbase = kc * 32 + (l >> 4) * 8;
    short v[8];
#pragma unroll
    for (int j = 0; j < 8; ++j) {
        int c = cbase + j;
        float w = 0.f;
        if (m < 80)        w = wc[((size_t)m * C + c) * 9 + tap];
        else if (m < 148)  w = wr[((size_t)(m - 80) * C + c) * 9 + tap];
        v[j] = f2bf(w);
    }
    *(bf16x8*)((short*)af + (size_t)idx * 8) = *(bf16x8*)v;
}

// ---------------------------------------------------------------------------
// NCHW fp32 -> [n][h*w][C] bf16 transpose; float4 global reads
// ---------------------------------------------------------------------------
template<int C, int H, int W>
__global__ __launch_bounds__(256) void transpose_x(const float* __restrict__ x,
                                                   __hip_bfloat16* __restrict__ xT) {
    const int CC = C / 64;
    int b   = blockIdx.x;
    int cch = b % CC;
    int y   = (b / CC) % H;
    int n   = b / (CC * H);
    __shared__ float sm[64][W + 1];
    const float* src = x + (((size_t)n * C + cch * 64) * H + y) * W;
    for (int i = threadIdx.x; i < 64 * (W / 4); i += 256) {
        int c = i / (W / 4), f4 = i % (W / 4);
        float4 v = *(const float4*)(src + (size_t)c * H * W + f4 * 4);
        sm[c][f4 * 4 + 0] = v.x;
        sm[c][f4 * 4 + 1] = v.y;
        sm[c][f4 * 4 + 2] = v.z;
        sm[c][f4 * 4 + 3] = v.w;
    }
    __syncthreads();
    short* dst = (short*)xT + ((size_t)n * H + y) * (size_t)W * C + cch * 64;
    for (int u = threadIdx.x; u < W * 8; u += 256) {
        int p = u >> 3, g = u & 7;
        short v[8];
#pragma unroll
        for (int j = 0; j < 8; ++j) v[j] = f2bf(sm[g * 8 + j][p]);
        *(bf16x8*)(dst + (size_t)p * C + g * 8) = *(bf16x8*)v;
    }
}

// ---------------------------------------------------------------------------
// Implicit-GEMM head, BOTH operands LDS-staged via global_load_lds.
// Block: 160 ch x NT px (NT=32*NF), 4 waves (2M x 2N), acc[5][NF]/wave.
// kc-outer / tap-inner: A granule (tap,kc)=10KB dbuf; B = flat pixel range
// [tile*NT-W-1, tile*NT+NT+W+1) x 32ch staged once per kc (covers all taps),
// staging of B[kc+1] spread across tap-steps. Taps read B from LDS with
// compile-time offset immediates; border taps zero-masked on the fragment.
// ---------------------------------------------------------------------------
template<int C, int H, int W, int STRIDE, int A_OFFp, int LVL, int NF, int NBLK>
__global__ __launch_bounds__(256, NBLK) void gemm_head(
    const __hip_bfloat16* __restrict__ xT,   // [n][HW][C] bf16
    const __hip_bfloat16* __restrict__ af,   // Afrag granule stream
    const float* __restrict__ bc, const float* __restrict__ br,
    const float* __restrict__ scales,
    float* __restrict__ out_cls, float* __restrict__ out_box) {
    constexpr int HW     = H * W;
    constexpr int NT     = NF * 32;
    constexpr int TILES  = (HW + NT - 1) / NT;
    constexpr int KC     = C / 32;
    constexpr int NSTAGE = NT + 2 * W + 2;
    constexpr int NS4    = NSTAGE * 4;
    constexpr int ITB    = (NS4 + 255) / 256;
    constexpr int BSZ    = ITB * 4096;
    constexpr int BBASE  = 2 * 10240;
    constexpr int LDSK   = BBASE + 2 * BSZ;
    constexpr int LDSB   = LDSK > 43520 ? LDSK : 43520;
    constexpr int ROUNDS = NT / 64;
    static_assert(ITB <= 9, "B staging spread exceeds tap steps");

    __shared__ __align__(16) char lds[LDSB];

    const int tile  = blockIdx.x % TILES;
    const int n     = blockIdx.x / TILES;
    const int tid   = threadIdx.x;
    const int l     = tid & 63;
    const int wid   = tid >> 6;
    const int mhalf = wid & 1;
    const int nhalf = wid >> 1;
    const int lr    = l & 15;
    const int kg    = l >> 4;

    const char* xb  = (const char*)xT + (size_t)n * HW * (C * 2);
    const char* afc = (const char*)af;
    const int pbase = tile * NT - (W + 1);

    // per-fragment tap masks + LDS lane addresses for B
    unsigned okm[NF];
    int blane[NF];
#pragma unroll
    for (int nf = 0; nf < NF; ++nf) {
        int p   = tile * NT + (nhalf * NF + nf) * 16 + lr;
        bool pv = p < HW;
        int pc  = pv ? p : HW - 1;
        int py  = pc / W, px = pc % W;
        unsigned m = 0;
#pragma unroll
        for (int tap = 0; tap < 9; ++tap) {
            int dy = tap / 3 - 1, dx = tap % 3 - 1;
            int y = py + dy, x = px + dx;
            if (pv && y >= 0 && y < H && x >= 0 && x < W) m |= 1u << tap;
        }
        okm[nf]   = m;
        blane[nf] = ((nhalf * NF + nf) * 16 + lr) * 64 + kg * 16;
    }

    f32x4 acc[5][NF];
#pragma unroll
    for (int mf = 0; mf < 5; ++mf)
#pragma unroll
        for (int nf = 0; nf < NF; ++nf) acc[mf][nf] = (f32x4)0.f;

    // prologue: stage A(tap0,kc0) into Abuf0, all of B(kc0) into Bbuf0
    {
#pragma unroll
        for (int it = 0; it < 3; ++it) {
            int idx = it * 256 + tid;
            if (idx < 640)
                stage16(afc + idx * 16, &lds[it * 4096 + wid * 1024]);
        }
#pragma unroll
        for (int it = 0; it < ITB; ++it) {
            int idx = it * 256 + tid;
            int pxr = idx >> 2; if (pxr > NSTAGE - 1) pxr = NSTAGE - 1;
            int pg = pbase + pxr; pg = pg < 0 ? 0 : (pg > HW - 1 ? HW - 1 : pg);
            stage16(xb + (size_t)pg * (C * 2) + (idx & 3) * 16,
                    &lds[BBASE + it * 4096 + wid * 1024]);
        }
    }
    __syncthreads();

    unsigned curA = 0, curB = 0;

#pragma unroll 1
    for (int kc = 0; kc < KC; ++kc) {
#pragma unroll
        for (int tap = 0; tap < 9; ++tap) {
            // stage next A granule into the other A buffer
            const int ntap = (tap == 8) ? 0 : tap + 1;
            const int nkc  = (tap == 8) ? kc + 1 : kc;
            if (nkc < KC) {
                const char* srcA = afc + (size_t)(ntap * KC + nkc) * 10240;
#pragma unroll
                for (int it = 0; it < 3; ++it) {
                    int idx = it * 256 + tid;
                    if (idx < 640)
                        stage16(srcA + idx * 16,
                                &lds[(curA ^ 10240) + it * 4096 + wid * 1024]);
                }
            }
            // stage B slice for kc+1, iteration 'tap' (spread across steps)
            if (tap < ITB && kc + 1 < KC) {
                int idx = tap * 256 + tid;
                int pxr = idx >> 2; if (pxr > NSTAGE - 1) pxr = NSTAGE - 1;
                int pg = pbase + pxr; pg = pg < 0 ? 0 : (pg > HW - 1 ? HW - 1 : pg);
                stage16(xb + (size_t)pg * (C * 2) + (kc + 1) * 64 + (idx & 3) * 16,
                        &lds[BBASE + (curB ^ BSZ) + tap * 4096 + wid * 1024]);
            }
            // compute: 5 A frags x NF B frags
            bf16x8 a[5];
#pragma unroll
            for (int mf = 0; mf < 5; ++mf)
                a[mf] = *(const bf16x8*)&lds[curA + (mhalf * 5 + mf) * 1024 + l * 16];
            const int imm = ((tap / 3) * W + (tap % 3)) * 64;  // ((dy+1)*W+(dx+1))*64
#pragma unroll
            for (int nf = 0; nf < NF; ++nf) {
                bf16x8 b = *(const bf16x8*)&lds[BBASE + curB + blane[nf] + imm];
                if (!((okm[nf] >> tap) & 1)) b = (bf16x8)(short)0;
#pragma unroll
                for (int mf = 0; mf < 5; ++mf)
                    acc[mf][nf] = __builtin_amdgcn_mfma_f32_16x16x32_bf16(
                        a[mf], b, acc[mf][nf], 0, 0, 0);
            }
            __syncthreads();
            curA ^= 10240;
            if (tap == 8) curB ^= BSZ;
        }
    }

    // fused epilogue, 64-px rounds through LDS [160][68]
    const float sc = scales[LVL];
    float* smf = (float*)lds;
#pragma unroll
    for (int rd = 0; rd < ROUNDS; ++rd) {
#pragma unroll
        for (int mf = 0; mf < 5; ++mf)
#pragma unroll
            for (int nf = 0; nf < NF; ++nf) {
                int colbase = (nhalf * NF + nf) * 16 - rd * 64;
                if (colbase >= 0 && colbase < 64) {
#pragma unroll
                    for (int r = 0; r < 4; ++r)
                        smf[(mhalf * 80 + mf * 16 + kg * 4 + r) * 68 + colbase + lr] =
                            acc[mf][nf][r];
                }
            }
        __syncthreads();
        const int t = tid & 63;
        const int q = wid;
        const int p = tile * NT + rd * 64 + t;
        if (p < HW) {
            const int py = p / W, px = p % W;
            const int a = A_OFFp + p;
            float* oc = out_cls + ((size_t)n * A_TOTAL + a) * NCLS + q * 20;
#pragma unroll
            for (int k = 0; k < 20; k += 4) {
                float4 v;
                v.x = 1.f / (1.f + expf(-(smf[(q * 20 + k + 0) * 68 + t] + bc[q * 20 + k + 0])));
                v.y = 1.f / (1.f + expf(-(smf[(q * 20 + k + 1) * 68 + t] + bc[q * 20 + k + 1])));
                v.z = 1.f / (1.f + expf(-(smf[(q * 20 + k + 2) * 68 + t] + bc[q * 20 + k + 2])));
                v.w = 1.f / (1.f + expf(-(smf[(q * 20 + k + 3) * 68 + t] + bc[q * 20 + k + 3])));
                *(float4*)(oc + k) = v;
            }
            float lgt[17];
            float m = -1e30f;
#pragma unroll
            for (int r = 0; r < 17; ++r) {
                lgt[r] = (smf[(80 + q * 17 + r) * 68 + t] + br[q * 17 + r]) * sc;
                m = fmaxf(m, lgt[r]);
            }
            float ssum = 0.f, esum = 0.f;
#pragma unroll
            for (int r = 0; r < 17; ++r) {
                float e = expf(lgt[r] - m);
                ssum += e;
                esum += e * (float)r;
            }
            const float dist = esum / ssum * (float)STRIDE;
            const float base = (q & 1) ? (float)(py * STRIDE) : (float)(px * STRIDE);
            const float val  = (q < 2) ? (base - dist) : (base + dist);
            out_box[((size_t)n * A_TOTAL + a) * 4 + q] = val;
        }
        __syncthreads();
    }
}

extern "C" void kernel_launch(void* const* d_in, const int* in_sizes, int n_in,
                              void* d_out, int out_size, void* d_ws, size_t ws_size,
                              hipStream_t stream) {
    const float* x0  = (const float*)d_in[0];
    const float* x1  = (const float*)d_in[1];
    const float* x2  = (const float*)d_in[2];
    const float* wc0 = (const float*)d_in[3];
    const float* bc0 = (const float*)d_in[4];
    const float* wr0 = (const float*)d_in[5];
    const float* br0 = (const float*)d_in[6];
    const float* wc1 = (const float*)d_in[7];
    const float* bc1 = (const float*)d_in[8];
    const float* wr1 = (const float*)d_in[9];
    const float* br1 = (const float*)d_in[10];
    const float* wc2 = (const float*)d_in[11];
    const float* bc2 = (const float*)d_in[12];
    const float* wr2 = (const float*)d_in[13];
    const float* br2 = (const float*)d_in[14];
    const float* scl = (const float*)d_in[15];

    float* out_cls = (float*)d_out;
    float* out_box = (float*)d_out + (size_t)BATCH * A_TOTAL * NCLS;

    __hip_bfloat16* af  = (__hip_bfloat16*)d_ws;
    __hip_bfloat16* af0 = af;
    __hip_bfloat16* af1 = af + 184320;
    __hip_bfloat16* af2 = af + 552960;
    __hip_bfloat16* xT  = af + 1290240;

    prep_w<128><<<dim3(90),  256, 0, stream>>>(wc0, wr0, af0);
    prep_w<256><<<dim3(180), 256, 0, stream>>>(wc1, wr1, af1);
    prep_w<512><<<dim3(360), 256, 0, stream>>>(wc2, wr2, af2);

    transpose_x<128, 80, 80><<<dim3(32 * 80 * 2), 256, 0, stream>>>(x0, xT);
    gemm_head<128, 80, 80, 8, 0, 0, 8, 2><<<dim3(BATCH * 25), 256, 0, stream>>>(
        xT, af0, bc0, br0, scl, out_cls, out_box);

    transpose_x<256, 40, 40><<<dim3(32 * 40 * 4), 256, 0, stream>>>(x1, xT);
    gemm_head<256, 40, 40, 16, 6400, 1, 4, 2><<<dim3(BATCH * 13), 256, 0, stream>>>(
        xT, af1, bc1, br1, scl, out_cls, out_box);

    transpose_x<512, 20, 20><<<dim3(32 * 20 * 8), 256, 0, stream>>>(x2, xT);
    gemm_head<512, 20, 20, 32, 8000, 2, 2, 3><<<dim3(BATCH * 7), 256, 0, stream>>>(
        xT, af2, bc2, br2, scl, out_cls, out_box);
}

// Round 5
// 396.766 us; speedup vs baseline: 1.1154x; 1.1154x over previous
//
#include <hip/hip_runtime.h>
#include <hip/hip_bf16.h>
#include <math.h>

#define BATCH   32
#define A_TOTAL 8400
#define NCLS    80

typedef __attribute__((ext_vector_type(8))) short bf16x8;
typedef __attribute__((ext_vector_type(4))) float f32x4;

__device__ __forceinline__ short f2bf(float f) {
    union { float f; unsigned u; } v; v.f = f;
    unsigned u = v.u + 0x7fffu + ((v.u >> 16) & 1u);   // round-nearest-even
    return (short)(u >> 16);
}

// async global->LDS, 16B per lane; lds dest = wave-uniform base + lane*16
__device__ __forceinline__ void stage16(const void* g, void* ldsp) {
    __builtin_amdgcn_global_load_lds(
        (const __attribute__((address_space(1))) unsigned int*)g,
        (__attribute__((address_space(3))) unsigned int*)ldsp, 16, 0, 0);
}

// ---------------------------------------------------------------------------
// Weight prep: Afrag[tap][kc][mf(10)][lane(64)][8] bf16, M padded 148->160.
// granule (tap, kc) = contiguous 10KB.
// ---------------------------------------------------------------------------
template<int C>
__global__ __launch_bounds__(256) void prep_w(const float* __restrict__ wc,
                                              const float* __restrict__ wr,
                                              __hip_bfloat16* __restrict__ af) {
    const int KC = C / 32;
    const int total = 9 * KC * 10 * 64;
    int idx = blockIdx.x * 256 + threadIdx.x;
    if (idx >= total) return;
    int l   = idx & 63;
    int rem = idx >> 6;
    int mf  = rem % 10;
    int kc  = (rem / 10) % KC;
    int tap = rem / (10 * KC);
    int m     = mf * 16 + (l & 15);
    int cbase = kc * 32 + (l >> 4) * 8;
    short v[8];
#pragma unroll
    for (int j = 0; j < 8; ++j) {
        int c = cbase + j;
        float w = 0.f;
        if (m < 80)        w = wc[((size_t)m * C + c) * 9 + tap];
        else if (m < 148)  w = wr[((size_t)(m - 80) * C + c) * 9 + tap];
        v[j] = f2bf(w);
    }
    *(bf16x8*)((short*)af + (size_t)idx * 8) = *(bf16x8*)v;
}

// ---------------------------------------------------------------------------
// NCHW fp32 -> xT[n][kc(C/32)][j(4)][HW][8 bf16] (16B granules, k-slot-major)
// ---------------------------------------------------------------------------
template<int C, int H, int W>
__global__ __launch_bounds__(256) void transpose_x(const float* __restrict__ x,
                                                   __hip_bfloat16* __restrict__ xT) {
    const int CC = C / 64;
    const int KC = C / 32;
    int b   = blockIdx.x;
    int cch = b % CC;
    int y   = (b / CC) % H;
    int n   = b / (CC * H);
    __shared__ float sm[64][W + 1];
    const float* src = x + (((size_t)n * C + cch * 64) * H + y) * W;
    for (int i = threadIdx.x; i < 64 * (W / 4); i += 256) {
        int c = i / (W / 4), f4 = i % (W / 4);
        float4 v = *(const float4*)(src + (size_t)c * H * W + f4 * 4);
        sm[c][f4 * 4 + 0] = v.x;
        sm[c][f4 * 4 + 1] = v.y;
        sm[c][f4 * 4 + 2] = v.z;
        sm[c][f4 * 4 + 3] = v.w;
    }
    __syncthreads();
    // u -> (g8 = u / W in 0..7, p = u % W); dst run contiguous in p
    for (int u = threadIdx.x; u < W * 8; u += 256) {
        int g8 = u / W, p = u % W;
        int kc = cch * 2 + (g8 >> 2);
        int j  = g8 & 3;
        short v[8];
#pragma unroll
        for (int jj = 0; jj < 8; ++jj) v[jj] = f2bf(sm[g8 * 8 + jj][p]);
        short* dst = (short*)xT +
            ((((size_t)n * KC + kc) * 4 + j) * (H * W) + (size_t)y * W + p) * 8;
        *(bf16x8*)dst = *(bf16x8*)v;
    }
}

// ---------------------------------------------------------------------------
// Implicit-GEMM head, BOTH operands LDS-staged via global_load_lds.
// Block: 160 ch x NT px (NT=32*NF), 4 waves (2M x 2N), acc[5][NF]/wave.
// B LDS layout [j(4)][NSTAGE][16B]: 16 consecutive lanes read 256 contiguous
// bytes (A-like, conflict-free). Tap = compile-time offset immediate.
// XCD-aware block swizzle (grid % 8 == 0) for halo L2 locality.
// ---------------------------------------------------------------------------
template<int C, int H, int W, int STRIDE, int A_OFFp, int LVL, int NF, int NBLK>
__global__ __launch_bounds__(256, NBLK) void gemm_head(
    const __hip_bfloat16* __restrict__ xT,   // [n][kc][j][HW][16B]
    const __hip_bfloat16* __restrict__ af,   // Afrag granule stream
    const float* __restrict__ bc, const float* __restrict__ br,
    const float* __restrict__ scales,
    float* __restrict__ out_cls, float* __restrict__ out_box) {
    constexpr int HW     = H * W;
    constexpr int NT     = NF * 32;
    constexpr int TILES  = (HW + NT - 1) / NT;
    constexpr int KC     = C / 32;
    constexpr int NSTAGE = NT + 2 * W + 2;
    constexpr int NS16   = NSTAGE * 16;
    constexpr int NS4    = NSTAGE * 4;
    constexpr int ITB    = (NS4 + 255) / 256;
    constexpr int BSZ    = ITB * 4096;
    constexpr int BBASE  = 2 * 10240;
    constexpr int LDSK   = BBASE + 2 * BSZ;
    constexpr int LDSB   = LDSK > 43520 ? LDSK : 43520;
    constexpr int ROUNDS = NT / 64;
    static_assert(ITB <= 9, "B staging spread exceeds tap steps");

    __shared__ __align__(16) char lds[LDSB];

    // XCD swizzle: contiguous tile chunks per XCD (grid multiple of 8)
    constexpr int NWG = BATCH * TILES;
    const int bid  = blockIdx.x;
    const int swz  = (bid & 7) * (NWG / 8) + (bid >> 3);
    const int tile = swz % TILES;
    const int n    = swz / TILES;

    const int tid   = threadIdx.x;
    const int l     = tid & 63;
    const int wid   = tid >> 6;
    const int mhalf = wid & 1;
    const int nhalf = wid >> 1;
    const int lr    = l & 15;
    const int kg    = l >> 4;

    const char* xb  = (const char*)xT + (size_t)n * KC * 4 * HW * 16;
    const char* afc = (const char*)af;
    const int pbase = tile * NT - (W + 1);

    // per-fragment tap masks + per-lane LDS base for B (j-major layout)
    unsigned okm[NF];
    int blane[NF];
#pragma unroll
    for (int nf = 0; nf < NF; ++nf) {
        int p   = tile * NT + (nhalf * NF + nf) * 16 + lr;
        bool pv = p < HW;
        int pc  = pv ? p : HW - 1;
        int py  = pc / W, px = pc % W;
        unsigned m = 0;
#pragma unroll
        for (int tap = 0; tap < 9; ++tap) {
            int dy = tap / 3 - 1, dx = tap % 3 - 1;
            int y = py + dy, x = px + dx;
            if (pv && y >= 0 && y < H && x >= 0 && x < W) m |= 1u << tap;
        }
        okm[nf]   = m;
        blane[nf] = kg * NS16 + ((nhalf * NF + nf) * 16 + lr) * 16;
    }

    f32x4 acc[5][NF];
#pragma unroll
    for (int mf = 0; mf < 5; ++mf)
#pragma unroll
        for (int nf = 0; nf < NF; ++nf) acc[mf][nf] = (f32x4)0.f;

    // B stage helper indices for linear lds idx -> (j, p) of kc slice
    auto stageB = [&](int it, int kc, unsigned dstbase) {
        int idx = it * 256 + tid;
        int j = (idx >= NSTAGE) + (idx >= 2 * NSTAGE) + (idx >= 3 * NSTAGE);
        int p = idx - j * NSTAGE;
        if (p > NSTAGE - 1) p = NSTAGE - 1;
        int pg = pbase + p;
        pg = pg < 0 ? 0 : (pg > HW - 1 ? HW - 1 : pg);
        stage16(xb + (((size_t)kc * 4 + j) * HW + pg) * 16,
                &lds[dstbase + it * 4096 + wid * 1024]);
    };

    // prologue: stage A(tap0,kc0) into Abuf0, all of B(kc0) into Bbuf0
    {
#pragma unroll
        for (int it = 0; it < 3; ++it) {
            int idx = it * 256 + tid;
            if (idx < 640)
                stage16(afc + idx * 16, &lds[it * 4096 + wid * 1024]);
        }
#pragma unroll
        for (int it = 0; it < ITB; ++it) stageB(it, 0, BBASE);
    }
    __syncthreads();

    unsigned curA = 0, curB = 0;

#pragma unroll 1
    for (int kc = 0; kc < KC; ++kc) {
#pragma unroll
        for (int tap = 0; tap < 9; ++tap) {
            // stage next A granule into the other A buffer
            const int ntap = (tap == 8) ? 0 : tap + 1;
            const int nkc  = (tap == 8) ? kc + 1 : kc;
            if (nkc < KC) {
                const char* srcA = afc + (size_t)(ntap * KC + nkc) * 10240;
#pragma unroll
                for (int it = 0; it < 3; ++it) {
                    int idx = it * 256 + tid;
                    if (idx < 640)
                        stage16(srcA + idx * 16,
                                &lds[(curA ^ 10240) + it * 4096 + wid * 1024]);
                }
            }
            // stage B slice for kc+1, spread across tap-steps
            if (tap < ITB && kc + 1 < KC)
                stageB(tap, kc + 1, BBASE + (curB ^ BSZ));
            // compute: 5 A frags x NF B frags
            bf16x8 a[5];
#pragma unroll
            for (int mf = 0; mf < 5; ++mf)
                a[mf] = *(const bf16x8*)&lds[curA + (mhalf * 5 + mf) * 1024 + l * 16];
            const int imm = ((tap / 3) * W + (tap % 3)) * 16;  // ((dy+1)*W+(dx+1))*16
#pragma unroll
            for (int nf = 0; nf < NF; ++nf) {
                bf16x8 b = *(const bf16x8*)&lds[BBASE + curB + blane[nf] + imm];
                if (!((okm[nf] >> tap) & 1)) b = (bf16x8)(short)0;
#pragma unroll
                for (int mf = 0; mf < 5; ++mf)
                    acc[mf][nf] = __builtin_amdgcn_mfma_f32_16x16x32_bf16(
                        a[mf], b, acc[mf][nf], 0, 0, 0);
            }
            __syncthreads();
            curA ^= 10240;
            if (tap == 8) curB ^= BSZ;
        }
    }

    // fused epilogue, 64-px rounds through LDS [160][68]
    const float sc = scales[LVL];
    float* smf = (float*)lds;
#pragma unroll
    for (int rd = 0; rd < ROUNDS; ++rd) {
#pragma unroll
        for (int mf = 0; mf < 5; ++mf)
#pragma unroll
            for (int nf = 0; nf < NF; ++nf) {
                int colbase = (nhalf * NF + nf) * 16 - rd * 64;
                if (colbase >= 0 && colbase < 64) {
#pragma unroll
                    for (int r = 0; r < 4; ++r)
                        smf[(mhalf * 80 + mf * 16 + kg * 4 + r) * 68 + colbase + lr] =
                            acc[mf][nf][r];
                }
            }
        __syncthreads();
        const int t = tid & 63;
        const int q = wid;
        const int p = tile * NT + rd * 64 + t;
        if (p < HW) {
            const int py = p / W, px = p % W;
            const int a = A_OFFp + p;
            float* oc = out_cls + ((size_t)n * A_TOTAL + a) * NCLS + q * 20;
#pragma unroll
            for (int k = 0; k < 20; k += 4) {
                float4 v;
                v.x = 1.f / (1.f + expf(-(smf[(q * 20 + k + 0) * 68 + t] + bc[q * 20 + k + 0])));
                v.y = 1.f / (1.f + expf(-(smf[(q * 20 + k + 1) * 68 + t] + bc[q * 20 + k + 1])));
                v.z = 1.f / (1.f + expf(-(smf[(q * 20 + k + 2) * 68 + t] + bc[q * 20 + k + 2])));
                v.w = 1.f / (1.f + expf(-(smf[(q * 20 + k + 3) * 68 + t] + bc[q * 20 + k + 3])));
                *(float4*)(oc + k) = v;
            }
            float lgt[17];
            float m = -1e30f;
#pragma unroll
            for (int r = 0; r < 17; ++r) {
                lgt[r] = (smf[(80 + q * 17 + r) * 68 + t] + br[q * 17 + r]) * sc;
                m = fmaxf(m, lgt[r]);
            }
            float ssum = 0.f, esum = 0.f;
#pragma unroll
            for (int r = 0; r < 17; ++r) {
                float e = expf(lgt[r] - m);
                ssum += e;
                esum += e * (float)r;
            }
            const float dist = esum / ssum * (float)STRIDE;
            const float base = (q & 1) ? (float)(py * STRIDE) : (float)(px * STRIDE);
            const float val  = (q < 2) ? (base - dist) : (base + dist);
            out_box[((size_t)n * A_TOTAL + a) * 4 + q] = val;
        }
        __syncthreads();
    }
}

extern "C" void kernel_launch(void* const* d_in, const int* in_sizes, int n_in,
                              void* d_out, int out_size, void* d_ws, size_t ws_size,
                              hipStream_t stream) {
    const float* x0  = (const float*)d_in[0];
    const float* x1  = (const float*)d_in[1];
    const float* x2  = (const float*)d_in[2];
    const float* wc0 = (const float*)d_in[3];
    const float* bc0 = (const float*)d_in[4];
    const float* wr0 = (const float*)d_in[5];
    const float* br0 = (const float*)d_in[6];
    const float* wc1 = (const float*)d_in[7];
    const float* bc1 = (const float*)d_in[8];
    const float* wr1 = (const float*)d_in[9];
    const float* br1 = (const float*)d_in[10];
    const float* wc2 = (const float*)d_in[11];
    const float* bc2 = (const float*)d_in[12];
    const float* wr2 = (const float*)d_in[13];
    const float* br2 = (const float*)d_in[14];
    const float* scl = (const float*)d_in[15];

    float* out_cls = (float*)d_out;
    float* out_box = (float*)d_out + (size_t)BATCH * A_TOTAL * NCLS;

    __hip_bfloat16* af  = (__hip_bfloat16*)d_ws;
    __hip_bfloat16* af0 = af;
    __hip_bfloat16* af1 = af + 184320;
    __hip_bfloat16* af2 = af + 552960;
    __hip_bfloat16* xT  = af + 1290240;

    prep_w<128><<<dim3(90),  256, 0, stream>>>(wc0, wr0, af0);
    prep_w<256><<<dim3(180), 256, 0, stream>>>(wc1, wr1, af1);
    prep_w<512><<<dim3(360), 256, 0, stream>>>(wc2, wr2, af2);

    transpose_x<128, 80, 80><<<dim3(32 * 80 * 2), 256, 0, stream>>>(x0, xT);
    gemm_head<128, 80, 80, 8, 0, 0, 8, 2><<<dim3(BATCH * 25), 256, 0, stream>>>(
        xT, af0, bc0, br0, scl, out_cls, out_box);

    transpose_x<256, 40, 40><<<dim3(32 * 40 * 4), 256, 0, stream>>>(x1, xT);
    gemm_head<256, 40, 40, 16, 6400, 1, 4, 3><<<dim3(BATCH * 13), 256, 0, stream>>>(
        xT, af1, bc1, br1, scl, out_cls, out_box);

    transpose_x<512, 20, 20><<<dim3(32 * 20 * 8), 256, 0, stream>>>(x2, xT);
    gemm_head<512, 20, 20, 32, 8000, 2, 2, 3><<<dim3(BATCH * 7), 256, 0, stream>>>(
        xT, af2, bc2, br2, scl, out_cls, out_box);
}

// Round 6
// 322.489 us; speedup vs baseline: 1.3723x; 1.2303x over previous
//
#include <hip/hip_runtime.h>
#include <hip/hip_bf16.h>
#include <math.h>

#define BATCH   32
#define A_TOTAL 8400
#define NCLS    80

typedef __attribute__((ext_vector_type(8))) short bf16x8;
typedef __attribute__((ext_vector_type(4))) float f32x4;

__device__ __forceinline__ short f2bf(float f) {
    union { float f; unsigned u; } v; v.f = f;
    unsigned u = v.u + 0x7fffu + ((v.u >> 16) & 1u);   // round-nearest-even
    return (short)(u >> 16);
}

// async global->LDS, 16B per lane; lds dest = wave-uniform base + lane*16
__device__ __forceinline__ void stage16(const void* g, void* ldsp) {
    __builtin_amdgcn_global_load_lds(
        (const __attribute__((address_space(1))) unsigned int*)g,
        (__attribute__((address_space(3))) unsigned int*)ldsp, 16, 0, 0);
}

// ---------------------------------------------------------------------------
// Weight prep: Afrag[tap][kc][mf(10)][lane(64)][8] bf16, M padded 148->160.
// granule (tap, kc) = contiguous 10KB.
// ---------------------------------------------------------------------------
template<int C>
__global__ __launch_bounds__(256) void prep_w(const float* __restrict__ wc,
                                              const float* __restrict__ wr,
                                              __hip_bfloat16* __restrict__ af) {
    const int KC = C / 32;
    const int total = 9 * KC * 10 * 64;
    int idx = blockIdx.x * 256 + threadIdx.x;
    if (idx >= total) return;
    int l   = idx & 63;
    int rem = idx >> 6;
    int mf  = rem % 10;
    int kc  = (rem / 10) % KC;
    int tap = rem / (10 * KC);
    int m     = mf * 16 + (l & 15);
    int cbase = kc * 32 + (l >> 4) * 8;
    short v[8];
#pragma unroll
    for (int j = 0; j < 8; ++j) {
        int c = cbase + j;
        float w = 0.f;
        if (m < 80)        w = wc[((size_t)m * C + c) * 9 + tap];
        else if (m < 148)  w = wr[((size_t)(m - 80) * C + c) * 9 + tap];
        v[j] = f2bf(w);
    }
    *(bf16x8*)((short*)af + (size_t)idx * 8) = *(bf16x8*)v;
}

// ---------------------------------------------------------------------------
// NCHW fp32 -> xT[n][kc(C/32)][j(4)][HW][8 bf16] (16B granules, k-slot-major)
// ---------------------------------------------------------------------------
template<int C, int H, int W>
__global__ __launch_bounds__(256) void transpose_x(const float* __restrict__ x,
                                                   __hip_bfloat16* __restrict__ xT) {
    const int CC = C / 64;
    const int KC = C / 32;
    int b   = blockIdx.x;
    int cch = b % CC;
    int y   = (b / CC) % H;
    int n   = b / (CC * H);
    __shared__ float sm[64][W + 1];
    const float* src = x + (((size_t)n * C + cch * 64) * H + y) * W;
    for (int i = threadIdx.x; i < 64 * (W / 4); i += 256) {
        int c = i / (W / 4), f4 = i % (W / 4);
        float4 v = *(const float4*)(src + (size_t)c * H * W + f4 * 4);
        sm[c][f4 * 4 + 0] = v.x;
        sm[c][f4 * 4 + 1] = v.y;
        sm[c][f4 * 4 + 2] = v.z;
        sm[c][f4 * 4 + 3] = v.w;
    }
    __syncthreads();
    for (int u = threadIdx.x; u < W * 8; u += 256) {
        int g8 = u / W, p = u % W;
        int kc = cch * 2 + (g8 >> 2);
        int j  = g8 & 3;
        short v[8];
#pragma unroll
        for (int jj = 0; jj < 8; ++jj) v[jj] = f2bf(sm[g8 * 8 + jj][p]);
        short* dst = (short*)xT +
            ((((size_t)n * KC + kc) * 4 + j) * (H * W) + (size_t)y * W + p) * 8;
        *(bf16x8*)dst = *(bf16x8*)v;
    }
}

// ---------------------------------------------------------------------------
// Implicit-GEMM head: A direct from L2 (weights are L2-resident, shared by all
// blocks), B double-buffered in LDS via global_load_lds. ONE barrier per kc:
// the 9-tap inner loop is barrier-free (taps read buffer cur; stages for kc+1
// write buffer other, issued in taps 0..ITB-1 so latency hides under compute).
// Block: 160 ch x NT px, 4 waves (2M x 2N), acc[5][NF]/wave.
// ---------------------------------------------------------------------------
template<int C, int H, int W, int STRIDE, int A_OFFp, int LVL, int NF, int NBLK>
__global__ __launch_bounds__(256, NBLK) void gemm_head(
    const __hip_bfloat16* __restrict__ xT,   // [n][kc][j][HW][16B]
    const __hip_bfloat16* __restrict__ af,   // Afrag granule stream
    const float* __restrict__ bc, const float* __restrict__ br,
    const float* __restrict__ scales,
    float* __restrict__ out_cls, float* __restrict__ out_box) {
    constexpr int HW     = H * W;
    constexpr int NT     = NF * 32;
    constexpr int TILES  = (HW + NT - 1) / NT;
    constexpr int KC     = C / 32;
    constexpr int NSTAGE = NT + 2 * W + 2;
    constexpr int NS16   = NSTAGE * 16;
    constexpr int NS4    = NSTAGE * 4;
    constexpr int ITB    = (NS4 + 255) / 256;
    constexpr int BSZ    = ITB * 4096;
    constexpr int LDSK   = 2 * BSZ;
    constexpr int LDSB   = LDSK > 43520 ? LDSK : 43520;
    constexpr int ROUNDS = NT / 64;
    static_assert(ITB <= 9, "B staging spread exceeds tap steps");

    __shared__ __align__(16) char lds[LDSB];

    // XCD swizzle: contiguous tile chunks per XCD (grid multiple of 8)
    constexpr int NWG = BATCH * TILES;
    const int bid  = blockIdx.x;
    const int swz  = (bid & 7) * (NWG / 8) + (bid >> 3);
    const int tile = swz % TILES;
    const int n    = swz / TILES;

    const int tid   = threadIdx.x;
    const int l     = tid & 63;
    const int wid   = tid >> 6;
    const int mhalf = wid & 1;
    const int nhalf = wid >> 1;
    const int lr    = l & 15;
    const int kg    = l >> 4;

    const char* xb  = (const char*)xT + (size_t)n * KC * 4 * HW * 16;
    const char* afc = (const char*)af;
    const int pbase = tile * NT - (W + 1);

    // per-fragment tap masks + per-lane LDS base for B (j-major layout)
    unsigned okm[NF];
    int blane[NF];
#pragma unroll
    for (int nf = 0; nf < NF; ++nf) {
        int p   = tile * NT + (nhalf * NF + nf) * 16 + lr;
        bool pv = p < HW;
        int pc  = pv ? p : HW - 1;
        int py  = pc / W, px = pc % W;
        unsigned m = 0;
#pragma unroll
        for (int tap = 0; tap < 9; ++tap) {
            int dy = tap / 3 - 1, dx = tap % 3 - 1;
            int y = py + dy, x = px + dx;
            if (pv && y >= 0 && y < H && x >= 0 && x < W) m |= 1u << tap;
        }
        okm[nf]   = m;
        blane[nf] = kg * NS16 + ((nhalf * NF + nf) * 16 + lr) * 16;
    }

    f32x4 acc[5][NF];
#pragma unroll
    for (int mf = 0; mf < 5; ++mf)
#pragma unroll
        for (int nf = 0; nf < NF; ++nf) acc[mf][nf] = (f32x4)0.f;

    // B stage helper: linear lds idx -> (j, p) of the kc slice
    auto stageB = [&](int it, int kc, unsigned dstbase) {
        int idx = it * 256 + tid;
        int j = (idx >= NSTAGE) + (idx >= 2 * NSTAGE) + (idx >= 3 * NSTAGE);
        int p = idx - j * NSTAGE;
        if (p > NSTAGE - 1) p = NSTAGE - 1;
        int pg = pbase + p;
        pg = pg < 0 ? 0 : (pg > HW - 1 ? HW - 1 : pg);
        stage16(xb + (((size_t)kc * 4 + j) * HW + pg) * 16,
                &lds[dstbase + it * 4096 + wid * 1024]);
    };

    // prologue: stage all of B(kc0) into buffer 0
#pragma unroll
    for (int it = 0; it < ITB; ++it) stageB(it, 0, 0);
    __syncthreads();

    unsigned curB = 0;

#pragma unroll 1
    for (int kc = 0; kc < KC; ++kc) {
#pragma unroll
        for (int tap = 0; tap < 9; ++tap) {
            // stage B slice for kc+1 into the other buffer (spread over taps)
            if (tap < ITB && kc + 1 < KC)
                stageB(tap, kc + 1, curB ^ BSZ);
            // A frags direct from L2 (1KB contiguous per wave-load)
            const char* asrc = afc + (size_t)(tap * KC + kc) * 10240 +
                               (mhalf * 5) * 1024 + l * 16;
            bf16x8 a[5];
#pragma unroll
            for (int mf = 0; mf < 5; ++mf)
                a[mf] = *(const bf16x8*)(asrc + mf * 1024);
            const int imm = ((tap / 3) * W + (tap % 3)) * 16;
#pragma unroll
            for (int nf = 0; nf < NF; ++nf) {
                bf16x8 b = *(const bf16x8*)&lds[curB + blane[nf] + imm];
                if (!((okm[nf] >> tap) & 1)) b = (bf16x8)(short)0;
#pragma unroll
                for (int mf = 0; mf < 5; ++mf)
                    acc[mf][nf] = __builtin_amdgcn_mfma_f32_16x16x32_bf16(
                        a[mf], b, acc[mf][nf], 0, 0, 0);
            }
        }
        __syncthreads();   // once per kc; stages issued >=4 taps ago -> cheap
        curB ^= BSZ;
    }

    // fused epilogue, 64-px rounds through LDS [160][68]
    const float sc = scales[LVL];
    float* smf = (float*)lds;
#pragma unroll
    for (int rd = 0; rd < ROUNDS; ++rd) {
#pragma unroll
        for (int mf = 0; mf < 5; ++mf)
#pragma unroll
            for (int nf = 0; nf < NF; ++nf) {
                int colbase = (nhalf * NF + nf) * 16 - rd * 64;
                if (colbase >= 0 && colbase < 64) {
#pragma unroll
                    for (int r = 0; r < 4; ++r)
                        smf[(mhalf * 80 + mf * 16 + kg * 4 + r) * 68 + colbase + lr] =
                            acc[mf][nf][r];
                }
            }
        __syncthreads();
        const int t = tid & 63;
        const int q = wid;
        const int p = tile * NT + rd * 64 + t;
        if (p < HW) {
            const int py = p / W, px = p % W;
            const int a = A_OFFp + p;
            float* oc = out_cls + ((size_t)n * A_TOTAL + a) * NCLS + q * 20;
#pragma unroll
            for (int k = 0; k < 20; k += 4) {
                float4 v;
                v.x = 1.f / (1.f + expf(-(smf[(q * 20 + k + 0) * 68 + t] + bc[q * 20 + k + 0])));
                v.y = 1.f / (1.f + expf(-(smf[(q * 20 + k + 1) * 68 + t] + bc[q * 20 + k + 1])));
                v.z = 1.f / (1.f + expf(-(smf[(q * 20 + k + 2) * 68 + t] + bc[q * 20 + k + 2])));
                v.w = 1.f / (1.f + expf(-(smf[(q * 20 + k + 3) * 68 + t] + bc[q * 20 + k + 3])));
                *(float4*)(oc + k) = v;
            }
            float lgt[17];
            float m = -1e30f;
#pragma unroll
            for (int r = 0; r < 17; ++r) {
                lgt[r] = (smf[(80 + q * 17 + r) * 68 + t] + br[q * 17 + r]) * sc;
                m = fmaxf(m, lgt[r]);
            }
            float ssum = 0.f, esum = 0.f;
#pragma unroll
            for (int r = 0; r < 17; ++r) {
                float e = expf(lgt[r] - m);
                ssum += e;
                esum += e * (float)r;
            }
            const float dist = esum / ssum * (float)STRIDE;
            const float base = (q & 1) ? (float)(py * STRIDE) : (float)(px * STRIDE);
            const float val  = (q < 2) ? (base - dist) : (base + dist);
            out_box[((size_t)n * A_TOTAL + a) * 4 + q] = val;
        }
        __syncthreads();
    }
}

extern "C" void kernel_launch(void* const* d_in, const int* in_sizes, int n_in,
                              void* d_out, int out_size, void* d_ws, size_t ws_size,
                              hipStream_t stream) {
    const float* x0  = (const float*)d_in[0];
    const float* x1  = (const float*)d_in[1];
    const float* x2  = (const float*)d_in[2];
    const float* wc0 = (const float*)d_in[3];
    const float* bc0 = (const float*)d_in[4];
    const float* wr0 = (const float*)d_in[5];
    const float* br0 = (const float*)d_in[6];
    const float* wc1 = (const float*)d_in[7];
    const float* bc1 = (const float*)d_in[8];
    const float* wr1 = (const float*)d_in[9];
    const float* br1 = (const float*)d_in[10];
    const float* wc2 = (const float*)d_in[11];
    const float* bc2 = (const float*)d_in[12];
    const float* wr2 = (const float*)d_in[13];
    const float* br2 = (const float*)d_in[14];
    const float* scl = (const float*)d_in[15];

    float* out_cls = (float*)d_out;
    float* out_box = (float*)d_out + (size_t)BATCH * A_TOTAL * NCLS;

    __hip_bfloat16* af  = (__hip_bfloat16*)d_ws;
    __hip_bfloat16* af0 = af;
    __hip_bfloat16* af1 = af + 184320;
    __hip_bfloat16* af2 = af + 552960;
    __hip_bfloat16* xT  = af + 1290240;

    prep_w<128><<<dim3(90),  256, 0, stream>>>(wc0, wr0, af0);
    prep_w<256><<<dim3(180), 256, 0, stream>>>(wc1, wr1, af1);
    prep_w<512><<<dim3(360), 256, 0, stream>>>(wc2, wr2, af2);

    transpose_x<128, 80, 80><<<dim3(32 * 80 * 2), 256, 0, stream>>>(x0, xT);
    gemm_head<128, 80, 80, 8, 0, 0, 4, 3><<<dim3(BATCH * 50), 256, 0, stream>>>(
        xT, af0, bc0, br0, scl, out_cls, out_box);

    transpose_x<256, 40, 40><<<dim3(32 * 40 * 4), 256, 0, stream>>>(x1, xT);
    gemm_head<256, 40, 40, 16, 6400, 1, 4, 3><<<dim3(BATCH * 13), 256, 0, stream>>>(
        xT, af1, bc1, br1, scl, out_cls, out_box);

    transpose_x<512, 20, 20><<<dim3(32 * 20 * 8), 256, 0, stream>>>(x2, xT);
    gemm_head<512, 20, 20, 32, 8000, 2, 2, 3><<<dim3(BATCH * 7), 256, 0, stream>>>(
        xT, af2, bc2, br2, scl, out_cls, out_box);
}